// Round 10
// baseline (332.137 us; speedup 1.0000x reference)
//
#include <hip/hip_runtime.h>

typedef unsigned short u16;
typedef __attribute__((ext_vector_type(8))) short short8;
typedef __attribute__((ext_vector_type(4))) short s16x4;
typedef __attribute__((ext_vector_type(4))) float f32x4;

#define CC 256
#define WW 128
#define HH 128
#define DD 32
#define NN 256
#define WH (WW * HH)
#define P8 524288        /* u16 per d-oct plane: G*N*8 = 256*256*8 */
#define OUTEL 16777216   /* out tensor elements */

__device__ __forceinline__ u16 f2bf(float f) {
  unsigned u = __float_as_uint(f);
  return (u16)((u + 0x7FFFu + ((u >> 16) & 1u)) >> 16);
}
__device__ __forceinline__ float bf2f(u16 h) {
  return __uint_as_float(((unsigned)h) << 16);
}

// ---------------- K0: pack Wq(32x256) + Wk(32x256) -> wqk[c][64] ----------------
__global__ __launch_bounds__(256) void k_pack(const float* __restrict__ Wq,
                                              const float* __restrict__ Wk,
                                              float* __restrict__ wqk) {
  int idx = blockIdx.x * 256 + threadIdx.x;  // 16384 total
  int r = idx >> 8, c = idx & 255;
  float v = (r < 32) ? Wq[r * 256 + c] : Wk[(r - 32) * 256 + c];
  wqk[c * 64 + r] = v;
}

// ---------------- K1: fp32 q/k projection + hi/lo bf16 split + xbf emit ----------------
// grid 256 groups x 1024 thr.  LDS-staged x (double-buffered 64-channel chunks).
// Also writes xbf[g][cin][m] bf16 (feeds the fused attention's X*att^T GEMM).
__global__ __launch_bounds__(1024) void k_qk(const float* __restrict__ x,
                                             const float* __restrict__ wqk,
                                             const float* __restrict__ bq,
                                             const float* __restrict__ bk,
                                             u16* __restrict__ qk,
                                             u16* __restrict__ xbf) {
  __shared__ float xs[2][64 * 256];  // 2 x 64 KiB
  int hw = blockIdx.x;
  int g = (hw & 7) * 32 + (hw >> 3);  // XCD-chunked: xcd = g>>5
  int bb = g >> 6, wb = (g >> 3) & 7, hb = g & 7;
  int w0 = wb * 16, h0 = hb * 16;
  int t = threadIdx.x, ln = t & 63;
  int dg = __builtin_amdgcn_readfirstlane(t >> 6);  // 0..15
  int dq4 = dg & 7, is_k = dg >> 3;
  const float* xwin = x + (size_t)bb * CC * WH + (size_t)w0 * HH + h0;
  u16* xbg = xbf + (size_t)g * CC * NN;

  // staging decomposition: lin = j*1024 + t in [0,4096): c = lin>>6, sub = lin&63
  f32x4 st[4];
#pragma unroll
  for (int j = 0; j < 4; ++j) {
    int lin = j * 1024 + t;
    int c = lin >> 6, sub = lin & 63;
    st[j] = *(const f32x4*)(xwin + (size_t)c * WH + (sub >> 2) * HH + (sub & 3) * 4);
  }
#pragma unroll
  for (int j = 0; j < 4; ++j) {
    int lin = j * 1024 + t;
    int c = lin >> 6, sub = lin & 63;
    *(f32x4*)&xs[0][c * 256 + sub * 4] = st[j];
    s16x4 bp;
#pragma unroll
    for (int i = 0; i < 4; ++i) bp[i] = (short)f2bf(st[j][i]);
    *(s16x4*)&xbg[(size_t)c * NN + sub * 4] = bp;
  }

  float acc[4][4];
#pragma unroll
  for (int j = 0; j < 4; ++j)
#pragma unroll
    for (int i = 0; i < 4; ++i) acc[j][i] = 0.f;

  for (int s = 0; s < 4; ++s) {
    int nxt = s + 1;
    if (nxt < 4) {
#pragma unroll
      for (int j = 0; j < 4; ++j) {
        int lin = j * 1024 + t;
        int c = lin >> 6, sub = lin & 63;
        st[j] = *(const f32x4*)(xwin + (size_t)(nxt * 64 + c) * WH + (sub >> 2) * HH +
                                (sub & 3) * 4);
      }
    }
    __syncthreads();
    const float* xb = xs[s & 1];
    const float* wp = wqk + (s * 64) * 64 + dg * 4;
#pragma unroll 4
    for (int cc = 0; cc < 64; ++cc) {
      f32x4 xv = *(const f32x4*)(xb + cc * 256 + 4 * ln);
      f32x4 wv4 = *(const f32x4*)(wp + cc * 64);
#pragma unroll
      for (int j = 0; j < 4; ++j)
#pragma unroll
        for (int i = 0; i < 4; ++i) acc[j][i] = fmaf(wv4[j], xv[i], acc[j][i]);
    }
    if (nxt < 4) {
#pragma unroll
      for (int j = 0; j < 4; ++j) {
        int lin = j * 1024 + t;
        int c = lin >> 6, sub = lin & 63;
        *(f32x4*)&xs[nxt & 1][c * 256 + sub * 4] = st[j];
        s16x4 bp;
#pragma unroll
        for (int i = 0; i < 4; ++i) bp[i] = (short)f2bf(st[j][i]);
        *(s16x4*)&xbg[(size_t)(nxt * 64 + c) * NN + sub * 4] = bp;
      }
    }
  }

  const float* bsrc = is_k ? bk : bq;
  float bias[4];
#pragma unroll
  for (int j = 0; j < 4; ++j) bias[j] = bsrc[dq4 * 4 + j];

  u16* ph = qk + ((size_t)((is_k << 3) + (dq4 >> 1))) * P8;
  int sub = (dq4 & 1) * 4;
#pragma unroll
  for (int i = 0; i < 4; ++i) {
    int m = 4 * ln + i;
    s16x4 hv, lv;
#pragma unroll
    for (int j = 0; j < 4; ++j) {
      float v = acc[j][i] + bias[j];
      u16 h = f2bf(v);
      hv[j] = (short)h;
      lv[j] = (short)f2bf(v - bf2f(h));
    }
    size_t ro = (size_t)(g * NN + m) * 8 + sub;
    *(s16x4*)(ph + ro) = hv;
    *(s16x4*)(ph + 4 * (size_t)P8 + ro) = lv;
  }
}

// ---------------- K2: fused attention, wave-independent (single barrier) ----------------
// grid 1024 = (g, n-quarter), 256 thr (4 waves).  Each wave owns 16 n-rows end-to-end:
// energy -> softmax -> att->own LDS rows -> per-wave GEMM1 Y[256cin][16n] -> att f32
// writeback -> Y^T->own LDS rows -> BARRIER -> block GEMM2 out=Wv*Y -> epilogue.
__global__ __launch_bounds__(256, 4) void k_attn(const float* __restrict__ x,
                                                 const float* __restrict__ Wv,
                                                 const float* __restrict__ bv,
                                                 const u16* __restrict__ qk,
                                                 const u16* __restrict__ xbf,
                                                 const float* __restrict__ gamma,
                                                 float* __restrict__ dout) {
  __shared__ u16 tile[64 * 256];  // 32 KiB: att rows, then (reused) Y^T rows
  int hw = blockIdx.x;
  int L = (hw & 7) * 128 + (hw >> 3);  // xcd = g>>5
  int g = L >> 2, qt = L & 3;
  int bb = g >> 6, wb = (g >> 3) & 7, hb = g & 7;
  int w0 = wb * 16, h0 = hb * 16;
  int t = threadIdx.x, ln = t & 63, wv = t >> 6;  // wv 0..3
  float gam = gamma[0];
  float* attg = dout + (size_t)OUTEL;
  char* smem = (char*)tile;
  int n0 = qt * 64;    // block's global n base
  int nw = wv * 16;    // wave's local row base in tile
  int nt = n0 + nw;    // wave's global n base
  int oct = ln >> 4;

  // ---- energy: e[n][m] for this wave's 16 n-rows x all 256 m ----
  const u16* qb = qk + (size_t)oct * P8 + (size_t)(g * NN + nt + (ln & 15)) * 8;
  short8 ahi = *(const short8*)qb;
  short8 alo = *(const short8*)(qb + 4 * (size_t)P8);
  f32x4 e[16];
#pragma unroll
  for (int mt = 0; mt < 16; ++mt) e[mt] = (f32x4){0.f, 0.f, 0.f, 0.f};
#pragma unroll
  for (int mt = 0; mt < 16; ++mt) {
    const u16* kb = qk + (size_t)(8 + oct) * P8 + (size_t)(g * NN + mt * 16 + (ln & 15)) * 8;
    short8 bhi = *(const short8*)kb;
    short8 blo = *(const short8*)(kb + 4 * (size_t)P8);
    e[mt] = __builtin_amdgcn_mfma_f32_16x16x32_bf16(ahi, bhi, e[mt], 0, 0, 0);
    e[mt] = __builtin_amdgcn_mfma_f32_16x16x32_bf16(alo, bhi, e[mt], 0, 0, 0);
    e[mt] = __builtin_amdgcn_mfma_f32_16x16x32_bf16(ahi, blo, e[mt], 0, 0, 0);
  }

  // ---- softmax over m: row n = nt + (ln>>4)*4 + r, spread over 16 lanes ----
  float inv[4];
#pragma unroll
  for (int r = 0; r < 4; ++r) {
    float m0 = e[0][r];
#pragma unroll
    for (int mt = 1; mt < 16; ++mt) m0 = fmaxf(m0, e[mt][r]);
    m0 = fmaxf(m0, __shfl_xor(m0, 1));
    m0 = fmaxf(m0, __shfl_xor(m0, 2));
    m0 = fmaxf(m0, __shfl_xor(m0, 4));
    m0 = fmaxf(m0, __shfl_xor(m0, 8));
    float s = 0.f;
#pragma unroll
    for (int mt = 0; mt < 16; ++mt) {
      float p = __expf(e[mt][r] - m0);
      e[mt][r] = p;
      s += p;
    }
    s += __shfl_xor(s, 1);
    s += __shfl_xor(s, 2);
    s += __shfl_xor(s, 4);
    s += __shfl_xor(s, 8);
    inv[r] = 1.0f / s;
  }

  // ---- att -> own LDS rows (bf16, 16B-granule XOR swizzle) ----
#pragma unroll
  for (int mt = 0; mt < 16; ++mt)
#pragma unroll
    for (int r = 0; r < 4; ++r) {
      int nn = nw + (ln >> 4) * 4 + r;
      int m = mt * 16 + (ln & 15);
      int byteoff = nn * 512 + ((2 * m) ^ ((nn & 7) << 4));
      *(u16*)(smem + byteoff) = f2bf(e[mt][r] * inv[r]);
    }

  // ---- per-wave GEMM1: Y[cin][n] = sum_m xbf[cin][m] * att[n][m], n = wave's 16 ----
  const u16* xbg = xbf + (size_t)g * CC * NN;
  f32x4 y[16];
#pragma unroll
  for (int ci = 0; ci < 16; ++ci) y[ci] = (f32x4){0.f, 0.f, 0.f, 0.f};
  {
    int nnb = nw + (ln & 15);
    int rowb = (ln & 15);
    int qoff = (ln >> 4) * 8;
#pragma unroll
    for (int c4 = 0; c4 < 4; ++c4)
#pragma unroll
      for (int kk = 0; kk < 8; ++kk) {
        int byteoff = nnb * 512 + ((2 * (kk * 32 + qoff)) ^ ((nnb & 7) << 4));
        short8 bfr = *(const short8*)(smem + byteoff);
#pragma unroll
        for (int c2 = 0; c2 < 4; ++c2) {
          int ci = c4 * 4 + c2;
          short8 a = *(const short8*)&xbg[(size_t)(ci * 16 + rowb) * NN + kk * 32 + qoff];
          y[ci] = __builtin_amdgcn_mfma_f32_16x16x32_bf16(a, bfr, y[ci], 0, 0, 0);
        }
      }
  }

  // ---- att f32 writeback (own 16 rows, coalesced 1KB/row) ----
#pragma unroll
  for (int r16 = 0; r16 < 16; ++r16) {
    int nn = nw + r16;
    int byteoff = nn * 512 + ((8 * ln) ^ ((nn & 7) << 4));
    s16x4 bv4 = *(const s16x4*)(smem + byteoff);
    f32x4 fv;
#pragma unroll
    for (int j = 0; j < 4; ++j) fv[j] = bf2f((u16)bv4[j]);
    *(f32x4*)(attg + (size_t)(g * NN + n0 + nn) * NN + 4 * ln) = fv;
  }

  // ---- Y^T -> own LDS rows (overwrites att; wave-local ordering via LDS FIFO) ----
  {
    int nn2 = nw + (ln & 15);
    int swz = (nn2 & 7) << 4;
#pragma unroll
    for (int ci = 0; ci < 16; ++ci) {
      s16x4 h;
#pragma unroll
      for (int r = 0; r < 4; ++r) h[r] = (short)f2bf(y[ci][r]);
      int byteoff = nn2 * 512 + ((32 * ci + 8 * (ln >> 4)) ^ swz);
      *(s16x4*)(smem + byteoff) = h;
    }
  }
  __syncthreads();

  // ---- GEMM2: out[c][n] = sum_cin Wv[c][cin] * Y[cin][n]; wave owns c-64 x n-64 ----
  int cbase = wv * 64;
  f32x4 o[4][4];
#pragma unroll
  for (int ci = 0; ci < 4; ++ci)
#pragma unroll
    for (int ni = 0; ni < 4; ++ni) o[ci][ni] = (f32x4){0.f, 0.f, 0.f, 0.f};

#pragma unroll
  for (int kk = 0; kk < 8; ++kk) {
    short8 wf[4];
#pragma unroll
    for (int ci = 0; ci < 4; ++ci) {
      int row = cbase + ci * 16 + (ln & 15);
      const float* wp = Wv + (size_t)row * CC + kk * 32 + (ln >> 4) * 8;
      f32x4 wa = *(const f32x4*)wp;
      f32x4 wb2 = *(const f32x4*)(wp + 4);
#pragma unroll
      for (int j = 0; j < 4; ++j) {
        wf[ci][j] = (short)f2bf(wa[j]);
        wf[ci][4 + j] = (short)f2bf(wb2[j]);
      }
    }
    short8 bfr2[4];
#pragma unroll
    for (int ni = 0; ni < 4; ++ni) {
      int nn = ni * 16 + (ln & 15);
      int byteoff = nn * 512 + ((2 * (kk * 32 + (ln >> 4) * 8)) ^ ((nn & 7) << 4));
      bfr2[ni] = *(const short8*)(smem + byteoff);
    }
#pragma unroll
    for (int ci = 0; ci < 4; ++ci)
#pragma unroll
      for (int ni = 0; ni < 4; ++ni)
        o[ci][ni] = __builtin_amdgcn_mfma_f32_16x16x32_bf16(wf[ci], bfr2[ni], o[ci][ni], 0, 0, 0);
  }

  // ---- epilogue: out = gamma*(pv + bv) + x ----
#pragma unroll
  for (int ci = 0; ci < 4; ++ci) {
    f32x4 bvv = *(const f32x4*)(bv + cbase + ci * 16 + (ln >> 4) * 4);
#pragma unroll
    for (int ni = 0; ni < 4; ++ni)
#pragma unroll
      for (int r = 0; r < 4; ++r) {
        int c = cbase + ci * 16 + (ln >> 4) * 4 + r;
        int n = n0 + ni * 16 + (ln & 15);
        size_t addr = (size_t)(bb * CC + c) * WH + (size_t)(w0 + (n >> 4)) * HH + h0 + (n & 15);
        dout[addr] = gam * (o[ci][ni][r] + bvv[r]) + x[addr];
      }
  }
}

extern "C" void kernel_launch(void* const* d_in, const int* in_sizes, int n_in,
                              void* d_out, int out_size, void* d_ws, size_t ws_size,
                              hipStream_t stream) {
  const float* x = (const float*)d_in[0];
  const float* Wq = (const float*)d_in[1];
  const float* bq = (const float*)d_in[2];
  const float* Wk = (const float*)d_in[3];
  const float* bk = (const float*)d_in[4];
  const float* Wv = (const float*)d_in[5];
  const float* bv = (const float*)d_in[6];
  const float* gamma = (const float*)d_in[7];
  float* out = (float*)d_out;

  float* wqk = (float*)d_ws;
  u16* qk = (u16*)((char*)d_ws + 65536);
  u16* xbf = qk + 16 * (size_t)P8;  // 32 MB

  k_pack<<<64, 256, 0, stream>>>(Wq, Wk, wqk);
  k_qk<<<256, 1024, 0, stream>>>(x, wqk, bq, bk, qk, xbf);
  k_attn<<<1024, 256, 0, stream>>>(x, Wv, bv, qk, xbf, gamma, out);
}